// Round 17
// baseline (186.468 us; speedup 1.0000x reference)
//
#include <hip/hip_runtime.h>
#include <hip/hip_bf16.h>

// Problem constants
#define BATCH 32
#define CCH   512
#define HWSZ  1024
#define RCH   256

typedef __attribute__((ext_vector_type(8))) _Float16 f16x8;
typedef __attribute__((ext_vector_type(4))) float f32x4;

__device__ __forceinline__ ushort f2h(float f) {
    _Float16 h = (_Float16)f;
    ushort u; __builtin_memcpy(&u, &h, 2);
    return u;
}
__device__ __forceinline__ float h2f(ushort u) {
    _Float16 h; __builtin_memcpy(&h, &u, 2);
    return (float)h;
}

__device__ __forceinline__ void load_lds16(const void* g, void* l) {
    __builtin_amdgcn_global_load_lds((const __attribute__((address_space(1))) void*)g,
                                     (__attribute__((address_space(3))) void*)l,
                                     16, 0, 0);
}

__device__ __forceinline__ f32x4 mfma16(f16x8 a, f16x8 b, f32x4 c) {
    return __builtin_amdgcn_mfma_f32_16x16x32_f16(a, b, c, 0, 0, 0);
}

// T1: bijective XCD-aware block swizzle (all grids divisible by 8)
__device__ __forceinline__ void xcd_swizzle(int& bx, int& by, int& bz) {
    int gx = gridDim.x, gy = gridDim.y;
    int n   = gx * gy * gridDim.z;
    int lin = bx + gx * (by + gy * bz);
    int cpx = n >> 3;
    int s = (lin & 7) * cpx + (lin >> 3);
    bx = s % gx; s /= gx;
    by = s % gy;
    bz = s / gy;
}

// ---------------- fused prep: z<32 = transpose x->xt (vectorized);
//                  z==32 = weight conversion (Wk||Wp, Wv) + bias stack
__global__ __launch_bounds__(256) void k_pre(
    const float* __restrict__ x, ushort* __restrict__ xt,
    const float* __restrict__ Wk, const float* __restrict__ bk,
    const float* __restrict__ Wp, const float* __restrict__ bp,
    const float* __restrict__ Wv,
    ushort* __restrict__ Wkp_h, ushort* __restrict__ Wv_h, float* __restrict__ bias_kp)
{
    __shared__ float tile[64][68];
    int t = threadIdx.x;
    if (blockIdx.z == 32) {
        int base = ((blockIdx.y * 16 + blockIdx.x) * 256 + t) * 8;
        int o = base >> 9, c = base & 511;
        const float* srcKP = (o < 256) ? (Wk + (size_t)o * 512 + c)
                                       : (Wp + (size_t)(o - 256) * 512 + c);
        float4 a0 = *(const float4*)srcKP;
        float4 a1 = *(const float4*)(srcKP + 4);
        ushort4 h0, h1;
        h0.x = f2h(a0.x); h0.y = f2h(a0.y); h0.z = f2h(a0.z); h0.w = f2h(a0.w);
        h1.x = f2h(a1.x); h1.y = f2h(a1.y); h1.z = f2h(a1.z); h1.w = f2h(a1.w);
        *(ushort4*)&Wkp_h[base] = h0;
        *(ushort4*)&Wkp_h[base + 4] = h1;
        float4 v0 = *(const float4*)(Wv + base);
        float4 v1 = *(const float4*)(Wv + base + 4);
        h0.x = f2h(v0.x); h0.y = f2h(v0.y); h0.z = f2h(v0.z); h0.w = f2h(v0.w);
        h1.x = f2h(v1.x); h1.y = f2h(v1.y); h1.z = f2h(v1.z); h1.w = f2h(v1.w);
        *(ushort4*)&Wv_h[base] = h0;
        *(ushort4*)&Wv_h[base + 4] = h1;
        if (c == 0) bias_kp[o] = (o < 256) ? bk[o] : bp[o - 256];
        return;
    }
    int b  = blockIdx.z;
    int c0 = blockIdx.y * 64;
    int n0 = blockIdx.x * 64;
    const float* xb = x + (size_t)b * CCH * HWSZ;
    int tc  = t >> 4;
    int tn4 = (t & 15) * 4;
    #pragma unroll
    for (int i = 0; i < 4; ++i) {
        int c = tc + i * 16;
        *(float4*)&tile[c][tn4] = *(const float4*)&xb[(size_t)(c0 + c) * HWSZ + n0 + tn4];
    }
    __syncthreads();
    ushort* oh = xt + (size_t)b * HWSZ * CCH;
    int tn  = t >> 4;
    int tc4 = (t & 15) * 4;
    #pragma unroll
    for (int i = 0; i < 4; ++i) {
        int n = tn + i * 16;
        ushort4 h;
        h.x = f2h(tile[tc4 + 0][n]);
        h.y = f2h(tile[tc4 + 1][n]);
        h.z = f2h(tile[tc4 + 2][n]);
        h.w = f2h(tile[tc4 + 3][n]);
        *(ushort4*)&oh[(size_t)(n0 + n) * CCH + c0 + tc4] = h;
    }
}

// ================= merged projections: one dispatch for KP + V (128x256 tiles,
// BK=32, 48KiB LDS -> 2 blocks/CU). z<32: V-proj batch z; z>=32: KP-proj.
__global__ __launch_bounds__(512, 4) void k_proj(
    const ushort* __restrict__ xt, const ushort* __restrict__ Wkp_h,
    const ushort* __restrict__ Wv_h, const float* __restrict__ bias_kp,
    const float* __restrict__ bv,
    ushort* __restrict__ KPt, ushort* __restrict__ fv)
{
    __shared__ ushort lds[2][12288];
    int bx = blockIdx.x, by = blockIdx.y, bz = blockIdx.z;
    xcd_swizzle(bx, by, bz);
    const int t    = threadIdx.x;
    const int lane = t & 63;
    const int w    = t >> 6;
    const int wm = w >> 2, wn = w & 3;
    const int l15 = lane & 15;
    const int hi  = lane >> 4;
    const int G   = hi ^ ((lane >> 1) & 3);
    const int sr = t >> 2;
    const int sg = (t & 3) ^ ((t >> 3) & 3);
    const int NT = CCH / 32;   // 16

    const ushort *Ab, *Bb;
    ushort* outp;
    const float* bias;
    int m0, n0, ldo;
    bool colB;
    if (bz < 32) {             // V-projection: fv[z][c][m] = Wv[c][:] . xt[z][m][:]
        Ab = Wv_h;
        Bb = xt + (size_t)bz * HWSZ * CCH;
        outp = fv + (size_t)bz * CCH * HWSZ;
        bias = bv; colB = false; ldo = HWSZ;
        m0 = bx * 128; n0 = by * 256;
    } else {                   // KP-projection: KPt[m][o] = xt[m][:] . Wkp[o][:]
        int idx = (bz - 32) * 16 + by * 4 + bx;   // 0..511
        Ab = xt; Bb = Wkp_h;
        outp = KPt; bias = bias_kp; colB = true; ldo = CCH;
        m0 = (idx >> 1) * 128; n0 = (idx & 1) * 256;
    }

    f32x4 acc[4][4] = {};
    f16x8 a[4], b01[2], b23[2];

#define STAGE(slot, kt) do {                                                 \
        size_t sa_ = (size_t)(m0 + sr) * CCH + (kt) * 32 + sg * 8;           \
        load_lds16(Ab + sa_, &lds[slot][t * 8]);                             \
        size_t sb_ = (size_t)(n0 + sr) * CCH + (kt) * 32 + sg * 8;           \
        load_lds16(Bb + sb_, &lds[slot][4096 + t * 8]);                      \
        load_lds16(Bb + sb_ + (size_t)128 * CCH, &lds[slot][8192 + t * 8]);  \
    } while (0)

#define RD_ALL(slot) do {                                                    \
        _Pragma("unroll")                                                    \
        for (int ni = 0; ni < 2; ++ni)                                       \
            b01[ni] = *(const f16x8*)&lds[slot][4096 + (wn * 64 + ni * 16 + l15) * 32 + G * 8]; \
        _Pragma("unroll")                                                    \
        for (int ni = 0; ni < 2; ++ni)                                       \
            b23[ni] = *(const f16x8*)&lds[slot][4096 + (wn * 64 + 32 + ni * 16 + l15) * 32 + G * 8]; \
        _Pragma("unroll")                                                    \
        for (int mi = 0; mi < 4; ++mi)                                       \
            a[mi] = *(const f16x8*)&lds[slot][(wm * 64 + mi * 16 + l15) * 32 + G * 8]; \
    } while (0)

#define BAR() __builtin_amdgcn_s_barrier()
#define WLG(N) do { asm volatile("s_waitcnt lgkmcnt(" #N ")" ::: "memory");  \
                    __builtin_amdgcn_sched_barrier(0); } while (0)
#define WVM(N) asm volatile("s_waitcnt vmcnt(" #N ")" ::: "memory")

#define MM4(mi) do {                                                         \
        acc[mi][0] = mfma16(a[mi], b01[0], acc[mi][0]);                      \
        acc[mi][1] = mfma16(a[mi], b01[1], acc[mi][1]);                      \
        acc[mi][2] = mfma16(a[mi], b23[0], acc[mi][2]);                      \
        acc[mi][3] = mfma16(a[mi], b23[1], acc[mi][3]);                      \
    } while (0)

#define MFMA_PIPE() do {                                                     \
        WLG(3); MM4(0); WLG(2); MM4(1); WLG(1); MM4(2); WLG(0); MM4(3);      \
    } while (0)

    STAGE(0, 0);
    WVM(0);
    BAR();
    for (int j = 0; j < NT - 1; ++j) {
        int cur = j & 1;
        STAGE(cur ^ 1, j + 1);
        RD_ALL(cur);
        MFMA_PIPE();
        WVM(0);
        BAR();
    }
    RD_ALL(1);
    MFMA_PIPE();

    #pragma unroll
    for (int mi = 0; mi < 4; ++mi) {
        #pragma unroll
        for (int ni = 0; ni < 4; ++ni) {
            int gc  = n0 + wn * 64 + (ni >> 1) * 32 + (ni & 1) * 16 + l15;
            int gr0 = m0 + wm * 64 + mi * 16 + hi * 4;
            #pragma unroll
            for (int jj = 0; jj < 4; ++jj) {
                int gr = gr0 + jj;
                float v = acc[mi][ni][jj] + (colB ? bias[gc] : bias[gr]);
                outp[(size_t)gr * ldo + gc] = f2h(v);
            }
        }
    }
#undef STAGE
#undef RD_ALL
#undef BAR
#undef WLG
#undef WVM
#undef MM4
#undef MFMA_PIPE
}

// ================= 256x256 GEMM, 2-barrier K-tiles + per-mi counted lgkmcnt.
// MODE 2 (energy): TWO n-tiles per block (n0 = by*512 + ny*256) sharing the
// staged A-panel -> prologue amortized, A refetch L2-warm, one block-round.
// MODE 3 (PV): single tile + residual f32 LDS-transpose epilogue.
template<int MODE>
__global__ __launch_bounds__(512, 2) void k_gemm256(
    const ushort* __restrict__ A, const ushort* __restrict__ B,
    int lda, int ldb, long aBatch, long bBatch,
    float* __restrict__ outF, ushort* __restrict__ out16,
    long oBatch, int ldo,
    const float* __restrict__ xres, const float* __restrict__ param,
    int NT)
{
    __shared__ ushort lds[2][2][2][8192];   // 128 KiB
    int bx = blockIdx.x, by = blockIdx.y, bz = blockIdx.z;
    xcd_swizzle(bx, by, bz);
    const int z  = bz;
    const int m0 = bx * 256;
    const int t    = threadIdx.x;
    const int lane = t & 63;
    const int w    = t >> 6;
    const int wm = w >> 2, wn = w & 3;
    const int l15 = lane & 15;
    const int hi  = lane >> 4;
    const int G   = hi ^ ((lane >> 1) & 3);

    const ushort* Ab = A + (size_t)z * aBatch;
    const ushort* Bb = B + (size_t)z * bBatch;

    const int sr = t >> 2;
    const int sg = (t & 3) ^ ((t >> 3) & 3);

    int n0;

#define STAGE(par, op, ks, kt) do {                                          \
        const ushort* gb_ = (op) ? Bb : Ab;                                  \
        int ld_ = (op) ? ldb : lda;                                          \
        int r0_ = (op) ? n0 : m0;                                            \
        size_t src_ = (size_t)(r0_ + sr) * ld_ + (kt) * 64 + (ks) * 32 + sg * 8; \
        load_lds16(gb_ + src_, &lds[par][op][ks][t * 8]);                    \
        load_lds16(gb_ + src_ + (size_t)128 * ld_, &lds[par][op][ks][t * 8 + 4096]); \
    } while (0)

#define LDA_(cur, ks) do {                                                   \
        _Pragma("unroll")                                                    \
        for (int mi = 0; mi < 8; ++mi)                                       \
            a[mi] = *(const f16x8*)&lds[cur][0][ks][(wm * 128 + mi * 16 + l15) * 32 + G * 8]; \
    } while (0)

#define LDB_(cur, ks, nh) do {                                               \
        _Pragma("unroll")                                                    \
        for (int ni = 0; ni < 2; ++ni)                                       \
            b[ni] = *(const f16x8*)&lds[cur][1][ks][(wn * 64 + (nh) * 32 + ni * 16 + l15) * 32 + G * 8]; \
    } while (0)

#define BAR() __builtin_amdgcn_s_barrier()

#define WLG(N) do { asm volatile("s_waitcnt lgkmcnt(" #N ")" ::: "memory");  \
                    __builtin_amdgcn_sched_barrier(0); } while (0)

#define MM2(mi, nh) do {                                                     \
        acc[mi][(nh)*2+0] = mfma16(a[mi], b[0], acc[mi][(nh)*2+0]);          \
        acc[mi][(nh)*2+1] = mfma16(a[mi], b[1], acc[mi][(nh)*2+1]);          \
    } while (0)

#define MFMA_PIPE() do {                                                     \
        WLG(7); MM2(0, 0); WLG(6); MM2(1, 0); WLG(5); MM2(2, 0);             \
        WLG(4); MM2(3, 0); WLG(3); MM2(4, 0); WLG(2); MM2(5, 0);             \
        WLG(1); MM2(6, 0); WLG(0); MM2(7, 0);                                \
    } while (0)

#define MFMA_BLK1() do {                                                     \
        WLG(0);                                                              \
        MM2(0, 1); MM2(1, 1); MM2(2, 1); MM2(3, 1);                          \
        MM2(4, 1); MM2(5, 1); MM2(6, 1); MM2(7, 1);                          \
    } while (0)

    const int nyN = (MODE == 2) ? 2 : 1;
    for (int ny = 0; ny < nyN; ++ny) {
        n0 = (MODE == 2) ? (by * 512 + ny * 256) : (by * 256);
        f32x4 acc[8][4] = {};
        f16x8 a[8], b[2];

        STAGE(0, 0, 0, 0); STAGE(0, 1, 0, 0); STAGE(0, 0, 1, 0); STAGE(0, 1, 1, 0);
        asm volatile("s_waitcnt vmcnt(4)" ::: "memory");
        BAR();

        for (int j = 0; j < NT - 1; ++j) {
            int cur = j & 1, nxt = cur ^ 1;
            STAGE(nxt, 0, 0, j + 1);
            LDB_(cur, 0, 0); LDA_(cur, 0);
            MFMA_PIPE();
            STAGE(nxt, 1, 0, j + 1);
            LDB_(cur, 0, 1);
            MFMA_BLK1();
            asm volatile("s_waitcnt vmcnt(4)" ::: "memory");
            BAR();
            STAGE(nxt, 0, 1, j + 1);
            LDB_(cur, 1, 0); LDA_(cur, 1);
            MFMA_PIPE();
            STAGE(nxt, 1, 1, j + 1);
            LDB_(cur, 1, 1);
            MFMA_BLK1();
            asm volatile("s_waitcnt vmcnt(4)" ::: "memory");
            BAR();
        }
        {
            int cur = (NT - 1) & 1;
            LDB_(cur, 0, 0); LDA_(cur, 0);
            MFMA_PIPE();
            LDB_(cur, 0, 1);
            MFMA_BLK1();
            asm volatile("s_waitcnt vmcnt(0)" ::: "memory");
            BAR();
            LDB_(cur, 1, 0); LDA_(cur, 1);
            MFMA_PIPE();
            LDB_(cur, 1, 1);
            MFMA_BLK1();
        }

        // ---------------- epilogue
        if (MODE == 3) {
            float* fbuf = (float*)lds;
            const float prm = param[0];
            float*       ob = outF + (size_t)z * oBatch;
            const float* xb = xres + (size_t)z * oBatch;
            #pragma unroll
            for (int h = 0; h < 2; ++h) {
                asm volatile("s_waitcnt lgkmcnt(0)" ::: "memory");
                BAR();
                if ((wn >> 1) == h) {
                    #pragma unroll
                    for (int mi = 0; mi < 8; ++mi)
                        #pragma unroll
                        for (int ni = 0; ni < 4; ++ni) {
                            int cc = (wn & 1) * 64 + (ni >> 1) * 32 + (ni & 1) * 16 + l15;
                            int nn = (wm * 128 + mi * 16 + hi * 4) ^ ((cc & 7) << 2);
                            *(f32x4*)&fbuf[cc * 256 + nn] = acc[mi][ni];
                        }
                }
                asm volatile("s_waitcnt lgkmcnt(0)" ::: "memory");
                BAR();
                #pragma unroll
                for (int rr = 0; rr < 16; ++rr) {
                    int cc = w * 16 + rr;
                    f32x4 o4 = *(const f32x4*)&fbuf[cc * 256 + ((lane * 4) ^ ((cc & 7) << 2))];
                    size_t g = (size_t)(n0 + h * 128 + cc) * ldo + m0 + lane * 4;
                    float4 xv = *(const float4*)&xb[g];
                    float4 ov;
                    ov.x = xv.x + o4[0] * prm;
                    ov.y = xv.y + o4[1] * prm;
                    ov.z = xv.z + o4[2] * prm;
                    ov.w = xv.w + o4[3] * prm;
                    *(float4*)&ob[g] = ov;
                }
            }
        } else {
            #pragma unroll
            for (int mi = 0; mi < 8; ++mi) {
                #pragma unroll
                for (int ni = 0; ni < 4; ++ni) {
                    int gc  = n0 + wn * 64 + (ni >> 1) * 32 + (ni & 1) * 16 + l15;
                    int gr0 = m0 + wm * 128 + mi * 16 + hi * 4;
                    #pragma unroll
                    for (int jj = 0; jj < 4; ++jj)
                        out16[(size_t)z * oBatch + (size_t)(gr0 + jj) * ldo + gc] = f2h(acc[mi][ni][jj]);
                }
            }
        }
    }
#undef STAGE
#undef LDA_
#undef LDB_
#undef BAR
#undef WLG
#undef MM2
#undef MFMA_PIPE
#undef MFMA_BLK1
}

// ---------------- row softmax over E (fp16, in place), 2 rows/block, 16B/lane
__global__ __launch_bounds__(256) void k_softmax(ushort* __restrict__ E)
{
    int t    = threadIdx.x;
    int rowi = t >> 7;                       // 0,1
    int tl   = t & 127;
    ushort* row = E + (size_t)(blockIdx.x * 2 + rowi) * HWSZ;
    uint4 u = *(const uint4*)&row[tl * 8];
    float v[8];
    v[0] = h2f(u.x & 0xffff); v[1] = h2f(u.x >> 16);
    v[2] = h2f(u.y & 0xffff); v[3] = h2f(u.y >> 16);
    v[4] = h2f(u.z & 0xffff); v[5] = h2f(u.z >> 16);
    v[6] = h2f(u.w & 0xffff); v[7] = h2f(u.w >> 16);
    float mx = v[0];
    #pragma unroll
    for (int i = 1; i < 8; ++i) mx = fmaxf(mx, v[i]);
    #pragma unroll
    for (int off = 1; off < 64; off <<= 1)
        mx = fmaxf(mx, __shfl_xor(mx, off));
    __shared__ float redm[2][2];
    __shared__ float reds[2][2];
    int lane = t & 63, wv = (t >> 6) & 1;
    if (lane == 0) redm[rowi][wv] = mx;
    __syncthreads();
    mx = fmaxf(redm[rowi][0], redm[rowi][1]);
    float s = 0.f;
    #pragma unroll
    for (int i = 0; i < 8; ++i) { v[i] = __expf(v[i] - mx); s += v[i]; }
    #pragma unroll
    for (int off = 1; off < 64; off <<= 1)
        s += __shfl_xor(s, off);
    if (lane == 0) reds[rowi][wv] = s;
    __syncthreads();
    s = reds[rowi][0] + reds[rowi][1];
    float inv = 1.0f / s;
    uint4 o;
    o.x = (unsigned)f2h(v[0] * inv) | ((unsigned)f2h(v[1] * inv) << 16);
    o.y = (unsigned)f2h(v[2] * inv) | ((unsigned)f2h(v[3] * inv) << 16);
    o.z = (unsigned)f2h(v[4] * inv) | ((unsigned)f2h(v[5] * inv) << 16);
    o.w = (unsigned)f2h(v[6] * inv) | ((unsigned)f2h(v[7] * inv) << 16);
    *(uint4*)&row[tl * 8] = o;
}

extern "C" void kernel_launch(void* const* d_in, const int* in_sizes, int n_in,
                              void* d_out, int out_size, void* d_ws, size_t ws_size,
                              hipStream_t stream)
{
    const float* x    = (const float*)d_in[0];
    const float* Wk   = (const float*)d_in[1];
    const float* bk   = (const float*)d_in[2];
    const float* Wp   = (const float*)d_in[3];
    const float* bp   = (const float*)d_in[4];
    const float* Wv   = (const float*)d_in[5];
    const float* bv   = (const float*)d_in[6];
    const float* prm  = (const float*)d_in[7];
    float* out = (float*)d_out;
    char* ws = (char*)d_ws;

    // workspace layout (bytes)
    const size_t SZ16 = (size_t)BATCH * HWSZ * CCH * 2;   // 33.55 MB
    ushort* xt    = (ushort*)(ws + 0);
    ushort* KPt   = (ushort*)(ws + SZ16);
    ushort* fv    = (ushort*)(ws + 2 * SZ16);
    ushort* E     = (ushort*)(ws + 3 * SZ16);             // fp16, 67.1 MB
    char* wbase   = ws + 3 * SZ16 + (size_t)BATCH * HWSZ * HWSZ * 2;
    ushort* Wkp_h = (ushort*)(wbase);
    ushort* Wv_h  = (ushort*)(wbase + 524288);
    float*  bias_kp = (float*)(wbase + 2 * 524288);

    // 1) fused weight prep + x transpose
    k_pre<<<dim3(16, 8, 33), 256, 0, stream>>>(
        x, xt, Wk, bk, Wp, bp, Wv, Wkp_h, Wv_h, bias_kp);

    // 2) merged projections: KP (512 blocks) + V (512 blocks) in one dispatch
    k_proj<<<dim3(4, 4, 64), 512, 0, stream>>>(
        xt, Wkp_h, Wv_h, bias_kp, bv, KPt, fv);

    // 3) energy (256-tile, 2 n-tiles/block): E[b][n][m] = Kt . Pt^T  (fp16 out)
    k_gemm256<2><<<dim3(4, 2, 32), 512, 0, stream>>>(
        KPt, KPt + RCH, CCH, CCH,
        (long)HWSZ * CCH, (long)HWSZ * CCH,
        nullptr, E, (long)HWSZ * HWSZ, HWSZ,
        nullptr, nullptr, RCH / 64);

    // 4) softmax rows -> sim fp16 (in place), 2 rows/block
    k_softmax<<<BATCH * HWSZ / 2, 256, 0, stream>>>(E);

    // 5) PV + residual (256-tile): out = x + (sim x fv^T)^T * param
    k_gemm256<3><<<dim3(4, 2, 32), 512, 0, stream>>>(
        E, fv, HWSZ, HWSZ,
        (long)HWSZ * HWSZ, (long)CCH * HWSZ,
        out, nullptr, (long)CCH * HWSZ, HWSZ,
        x, prm, HWSZ / 64);
}

// Round 18
// 175.997 us; speedup vs baseline: 1.0595x; 1.0595x over previous
//
#include <hip/hip_runtime.h>
#include <hip/hip_bf16.h>

// Problem constants
#define BATCH 32
#define CCH   512
#define HWSZ  1024
#define RCH   256

typedef __attribute__((ext_vector_type(8))) _Float16 f16x8;
typedef __attribute__((ext_vector_type(4))) float f32x4;

__device__ __forceinline__ ushort f2h(float f) {
    _Float16 h = (_Float16)f;
    ushort u; __builtin_memcpy(&u, &h, 2);
    return u;
}
__device__ __forceinline__ float h2f(ushort u) {
    _Float16 h; __builtin_memcpy(&h, &u, 2);
    return (float)h;
}

__device__ __forceinline__ void load_lds16(const void* g, void* l) {
    __builtin_amdgcn_global_load_lds((const __attribute__((address_space(1))) void*)g,
                                     (__attribute__((address_space(3))) void*)l,
                                     16, 0, 0);
}

__device__ __forceinline__ f32x4 mfma16(f16x8 a, f16x8 b, f32x4 c) {
    return __builtin_amdgcn_mfma_f32_16x16x32_f16(a, b, c, 0, 0, 0);
}

// T1: bijective XCD-aware block swizzle (all grids divisible by 8)
__device__ __forceinline__ void xcd_swizzle(int& bx, int& by, int& bz) {
    int gx = gridDim.x, gy = gridDim.y;
    int n   = gx * gy * gridDim.z;
    int lin = bx + gx * (by + gy * bz);
    int cpx = n >> 3;
    int s = (lin & 7) * cpx + (lin >> 3);
    bx = s % gx; s /= gx;
    by = s % gy;
    bz = s / gy;
}

// ---------------- fused prep: z<32 = transpose x->xt (vectorized);
//                  z==32 = weight conversion (Wk||Wp, Wv) + bias stack
__global__ __launch_bounds__(256) void k_pre(
    const float* __restrict__ x, ushort* __restrict__ xt,
    const float* __restrict__ Wk, const float* __restrict__ bk,
    const float* __restrict__ Wp, const float* __restrict__ bp,
    const float* __restrict__ Wv,
    ushort* __restrict__ Wkp_h, ushort* __restrict__ Wv_h, float* __restrict__ bias_kp)
{
    __shared__ float tile[64][68];
    int t = threadIdx.x;
    if (blockIdx.z == 32) {
        int base = ((blockIdx.y * 16 + blockIdx.x) * 256 + t) * 8;
        int o = base >> 9, c = base & 511;
        const float* srcKP = (o < 256) ? (Wk + (size_t)o * 512 + c)
                                       : (Wp + (size_t)(o - 256) * 512 + c);
        float4 a0 = *(const float4*)srcKP;
        float4 a1 = *(const float4*)(srcKP + 4);
        ushort4 h0, h1;
        h0.x = f2h(a0.x); h0.y = f2h(a0.y); h0.z = f2h(a0.z); h0.w = f2h(a0.w);
        h1.x = f2h(a1.x); h1.y = f2h(a1.y); h1.z = f2h(a1.z); h1.w = f2h(a1.w);
        *(ushort4*)&Wkp_h[base] = h0;
        *(ushort4*)&Wkp_h[base + 4] = h1;
        float4 v0 = *(const float4*)(Wv + base);
        float4 v1 = *(const float4*)(Wv + base + 4);
        h0.x = f2h(v0.x); h0.y = f2h(v0.y); h0.z = f2h(v0.z); h0.w = f2h(v0.w);
        h1.x = f2h(v1.x); h1.y = f2h(v1.y); h1.z = f2h(v1.z); h1.w = f2h(v1.w);
        *(ushort4*)&Wv_h[base] = h0;
        *(ushort4*)&Wv_h[base + 4] = h1;
        if (c == 0) bias_kp[o] = (o < 256) ? bk[o] : bp[o - 256];
        return;
    }
    int b  = blockIdx.z;
    int c0 = blockIdx.y * 64;
    int n0 = blockIdx.x * 64;
    const float* xb = x + (size_t)b * CCH * HWSZ;
    int tc  = t >> 4;
    int tn4 = (t & 15) * 4;
    #pragma unroll
    for (int i = 0; i < 4; ++i) {
        int c = tc + i * 16;
        *(float4*)&tile[c][tn4] = *(const float4*)&xb[(size_t)(c0 + c) * HWSZ + n0 + tn4];
    }
    __syncthreads();
    ushort* oh = xt + (size_t)b * HWSZ * CCH;
    int tn  = t >> 4;
    int tc4 = (t & 15) * 4;
    #pragma unroll
    for (int i = 0; i < 4; ++i) {
        int n = tn + i * 16;
        ushort4 h;
        h.x = f2h(tile[tc4 + 0][n]);
        h.y = f2h(tile[tc4 + 1][n]);
        h.z = f2h(tile[tc4 + 2][n]);
        h.w = f2h(tile[tc4 + 3][n]);
        *(ushort4*)&oh[(size_t)(n0 + n) * CCH + c0 + tc4] = h;
    }
}

// ================= 128x256 GEMM, BK=32, 48KiB LDS -> 2 blocks/CU (R14).
// Best for the projection GEMMs (KP, V): long K, small grids, occupancy-bound.
template<int MODE>
__global__ __launch_bounds__(512, 4) void k_gemm128(
    const ushort* __restrict__ A, const ushort* __restrict__ B,
    int lda, int ldb, long aBatch, long bBatch,
    ushort* __restrict__ out16, long oBatch, int ldo,
    const float* __restrict__ bias, int NT)
{
    __shared__ ushort lds[2][12288];
    int bx = blockIdx.x, by = blockIdx.y, bz = blockIdx.z;
    xcd_swizzle(bx, by, bz);
    const int z  = bz;
    const int m0 = bx * 128;
    const int n0 = by * 256;
    const int t    = threadIdx.x;
    const int lane = t & 63;
    const int w    = t >> 6;
    const int wm = w >> 2, wn = w & 3;
    const int l15 = lane & 15;
    const int hi  = lane >> 4;
    const int G   = hi ^ ((lane >> 1) & 3);

    const ushort* Ab = A + (size_t)z * aBatch;
    const ushort* Bb = B + (size_t)z * bBatch;

    const int sr = t >> 2;
    const int sg = (t & 3) ^ ((t >> 3) & 3);

    f32x4 acc[4][4] = {};
    f16x8 a[4], b01[2], b23[2];

#define STAGE(slot, kt) do {                                                 \
        size_t sa_ = (size_t)(m0 + sr) * lda + (kt) * 32 + sg * 8;           \
        load_lds16(Ab + sa_, &lds[slot][t * 8]);                             \
        size_t sb_ = (size_t)(n0 + sr) * ldb + (kt) * 32 + sg * 8;           \
        load_lds16(Bb + sb_, &lds[slot][4096 + t * 8]);                      \
        load_lds16(Bb + sb_ + (size_t)128 * ldb, &lds[slot][8192 + t * 8]);  \
    } while (0)

#define RD_ALL(slot) do {                                                    \
        _Pragma("unroll")                                                    \
        for (int ni = 0; ni < 2; ++ni)                                       \
            b01[ni] = *(const f16x8*)&lds[slot][4096 + (wn * 64 + ni * 16 + l15) * 32 + G * 8]; \
        _Pragma("unroll")                                                    \
        for (int ni = 0; ni < 2; ++ni)                                       \
            b23[ni] = *(const f16x8*)&lds[slot][4096 + (wn * 64 + 32 + ni * 16 + l15) * 32 + G * 8]; \
        _Pragma("unroll")                                                    \
        for (int mi = 0; mi < 4; ++mi)                                       \
            a[mi] = *(const f16x8*)&lds[slot][(wm * 64 + mi * 16 + l15) * 32 + G * 8]; \
    } while (0)

#define BAR() __builtin_amdgcn_s_barrier()
#define WLG(N) do { asm volatile("s_waitcnt lgkmcnt(" #N ")" ::: "memory");  \
                    __builtin_amdgcn_sched_barrier(0); } while (0)
#define WVM(N) asm volatile("s_waitcnt vmcnt(" #N ")" ::: "memory")

#define MM4(mi) do {                                                         \
        acc[mi][0] = mfma16(a[mi], b01[0], acc[mi][0]);                      \
        acc[mi][1] = mfma16(a[mi], b01[1], acc[mi][1]);                      \
        acc[mi][2] = mfma16(a[mi], b23[0], acc[mi][2]);                      \
        acc[mi][3] = mfma16(a[mi], b23[1], acc[mi][3]);                      \
    } while (0)

#define MFMA_PIPE() do {                                                     \
        WLG(3); MM4(0); WLG(2); MM4(1); WLG(1); MM4(2); WLG(0); MM4(3);      \
    } while (0)

    STAGE(0, 0);
    WVM(0);
    BAR();
    for (int j = 0; j < NT - 1; ++j) {
        int cur = j & 1;
        STAGE(cur ^ 1, j + 1);
        RD_ALL(cur);
        MFMA_PIPE();
        WVM(0);
        BAR();
    }
    RD_ALL(1);
    MFMA_PIPE();

    #pragma unroll
    for (int mi = 0; mi < 4; ++mi) {
        #pragma unroll
        for (int ni = 0; ni < 4; ++ni) {
            int gc  = n0 + wn * 64 + (ni >> 1) * 32 + (ni & 1) * 16 + l15;
            int gr0 = m0 + wm * 64 + mi * 16 + hi * 4;
            #pragma unroll
            for (int jj = 0; jj < 4; ++jj) {
                int gr = gr0 + jj;
                float v = acc[mi][ni][jj];
                if (MODE == 0) {
                    v += bias[gc];
                    out16[(size_t)gr * ldo + gc] = f2h(v);
                } else {
                    v += bias[gr];
                    out16[(size_t)z * oBatch + (size_t)gr * ldo + gc] = f2h(v);
                }
            }
        }
    }
#undef STAGE
#undef RD_ALL
#undef BAR
#undef WLG
#undef WVM
#undef MM4
#undef MFMA_PIPE
}

// ================= 256x256 GEMM, 2-barrier K-tiles + per-mi counted lgkmcnt (R12).
// Best for the attention GEMMs (energy, PV): short K, big panel reuse.
// MODE 2: energy -> fp16. MODE 3: PV + residual via f32 LDS-transpose epilogue.
template<int MODE>
__global__ __launch_bounds__(512, 2) void k_gemm256(
    const ushort* __restrict__ A, const ushort* __restrict__ B,
    int lda, int ldb, long aBatch, long bBatch,
    float* __restrict__ outF, ushort* __restrict__ out16,
    long oBatch, int ldo,
    const float* __restrict__ xres, const float* __restrict__ param,
    int NT)
{
    __shared__ ushort lds[2][2][2][8192];   // 128 KiB
    int bx = blockIdx.x, by = blockIdx.y, bz = blockIdx.z;
    xcd_swizzle(bx, by, bz);
    const int z  = bz;
    const int m0 = bx * 256;
    const int n0 = by * 256;
    const int t    = threadIdx.x;
    const int lane = t & 63;
    const int w    = t >> 6;
    const int wm = w >> 2, wn = w & 3;
    const int l15 = lane & 15;
    const int hi  = lane >> 4;
    const int G   = hi ^ ((lane >> 1) & 3);

    const ushort* Ab = A + (size_t)z * aBatch;
    const ushort* Bb = B + (size_t)z * bBatch;

    const int sr = t >> 2;
    const int sg = (t & 3) ^ ((t >> 3) & 3);

    f32x4 acc[8][4] = {};
    f16x8 a[8], b[2];

#define STAGE(par, op, ks, kt) do {                                          \
        const ushort* gb_ = (op) ? Bb : Ab;                                  \
        int ld_ = (op) ? ldb : lda;                                          \
        int r0_ = (op) ? n0 : m0;                                            \
        size_t src_ = (size_t)(r0_ + sr) * ld_ + (kt) * 64 + (ks) * 32 + sg * 8; \
        load_lds16(gb_ + src_, &lds[par][op][ks][t * 8]);                    \
        load_lds16(gb_ + src_ + (size_t)128 * ld_, &lds[par][op][ks][t * 8 + 4096]); \
    } while (0)

#define LDA_(cur, ks) do {                                                   \
        _Pragma("unroll")                                                    \
        for (int mi = 0; mi < 8; ++mi)                                       \
            a[mi] = *(const f16x8*)&lds[cur][0][ks][(wm * 128 + mi * 16 + l15) * 32 + G * 8]; \
    } while (0)

#define LDB_(cur, ks, nh) do {                                               \
        _Pragma("unroll")                                                    \
        for (int ni = 0; ni < 2; ++ni)                                       \
            b[ni] = *(const f16x8*)&lds[cur][1][ks][(wn * 64 + (nh) * 32 + ni * 16 + l15) * 32 + G * 8]; \
    } while (0)

#define BAR() __builtin_amdgcn_s_barrier()

#define WLG(N) do { asm volatile("s_waitcnt lgkmcnt(" #N ")" ::: "memory");  \
                    __builtin_amdgcn_sched_barrier(0); } while (0)

#define MM2(mi, nh) do {                                                     \
        acc[mi][(nh)*2+0] = mfma16(a[mi], b[0], acc[mi][(nh)*2+0]);          \
        acc[mi][(nh)*2+1] = mfma16(a[mi], b[1], acc[mi][(nh)*2+1]);          \
    } while (0)

#define MFMA_PIPE() do {                                                     \
        WLG(7); MM2(0, 0); WLG(6); MM2(1, 0); WLG(5); MM2(2, 0);             \
        WLG(4); MM2(3, 0); WLG(3); MM2(4, 0); WLG(2); MM2(5, 0);             \
        WLG(1); MM2(6, 0); WLG(0); MM2(7, 0);                                \
    } while (0)

#define MFMA_BLK1() do {                                                     \
        WLG(0);                                                              \
        MM2(0, 1); MM2(1, 1); MM2(2, 1); MM2(3, 1);                          \
        MM2(4, 1); MM2(5, 1); MM2(6, 1); MM2(7, 1);                          \
    } while (0)

    STAGE(0, 0, 0, 0); STAGE(0, 1, 0, 0); STAGE(0, 0, 1, 0); STAGE(0, 1, 1, 0);
    asm volatile("s_waitcnt vmcnt(4)" ::: "memory");
    BAR();

    for (int j = 0; j < NT - 1; ++j) {
        int cur = j & 1, nxt = cur ^ 1;
        STAGE(nxt, 0, 0, j + 1);
        LDB_(cur, 0, 0); LDA_(cur, 0);
        MFMA_PIPE();
        STAGE(nxt, 1, 0, j + 1);
        LDB_(cur, 0, 1);
        MFMA_BLK1();
        asm volatile("s_waitcnt vmcnt(4)" ::: "memory");
        BAR();
        STAGE(nxt, 0, 1, j + 1);
        LDB_(cur, 1, 0); LDA_(cur, 1);
        MFMA_PIPE();
        STAGE(nxt, 1, 1, j + 1);
        LDB_(cur, 1, 1);
        MFMA_BLK1();
        asm volatile("s_waitcnt vmcnt(4)" ::: "memory");
        BAR();
    }
    {
        int cur = (NT - 1) & 1;
        LDB_(cur, 0, 0); LDA_(cur, 0);
        MFMA_PIPE();
        LDB_(cur, 0, 1);
        MFMA_BLK1();
        asm volatile("s_waitcnt vmcnt(0)" ::: "memory");
        BAR();
        LDB_(cur, 1, 0); LDA_(cur, 1);
        MFMA_PIPE();
        LDB_(cur, 1, 1);
        MFMA_BLK1();
    }

    // ---------------- epilogue
    if (MODE == 3) {
        float* fbuf = (float*)lds;
        const float prm = param[0];
        float*       ob = outF + (size_t)z * oBatch;
        const float* xb = xres + (size_t)z * oBatch;
        #pragma unroll
        for (int h = 0; h < 2; ++h) {
            asm volatile("s_waitcnt lgkmcnt(0)" ::: "memory");
            BAR();
            if ((wn >> 1) == h) {
                #pragma unroll
                for (int mi = 0; mi < 8; ++mi)
                    #pragma unroll
                    for (int ni = 0; ni < 4; ++ni) {
                        int cc = (wn & 1) * 64 + (ni >> 1) * 32 + (ni & 1) * 16 + l15;
                        int nn = (wm * 128 + mi * 16 + hi * 4) ^ ((cc & 7) << 2);
                        *(f32x4*)&fbuf[cc * 256 + nn] = acc[mi][ni];
                    }
            }
            asm volatile("s_waitcnt lgkmcnt(0)" ::: "memory");
            BAR();
            #pragma unroll
            for (int rr = 0; rr < 16; ++rr) {
                int cc = w * 16 + rr;
                f32x4 o4 = *(const f32x4*)&fbuf[cc * 256 + ((lane * 4) ^ ((cc & 7) << 2))];
                size_t g = (size_t)(n0 + h * 128 + cc) * ldo + m0 + lane * 4;
                float4 xv = *(const float4*)&xb[g];
                float4 ov;
                ov.x = xv.x + o4[0] * prm;
                ov.y = xv.y + o4[1] * prm;
                ov.z = xv.z + o4[2] * prm;
                ov.w = xv.w + o4[3] * prm;
                *(float4*)&ob[g] = ov;
            }
        }
    } else {
        #pragma unroll
        for (int mi = 0; mi < 8; ++mi) {
            #pragma unroll
            for (int ni = 0; ni < 4; ++ni) {
                int gc  = n0 + wn * 64 + (ni >> 1) * 32 + (ni & 1) * 16 + l15;
                int gr0 = m0 + wm * 128 + mi * 16 + hi * 4;
                #pragma unroll
                for (int jj = 0; jj < 4; ++jj) {
                    out16[(size_t)z * oBatch + (size_t)(gr0 + jj) * ldo + gc] = f2h(acc[mi][ni][jj]);
                }
            }
        }
    }
#undef STAGE
#undef LDA_
#undef LDB_
#undef BAR
#undef WLG
#undef MM2
#undef MFMA_PIPE
#undef MFMA_BLK1
}

// ---------------- row softmax over E (fp16, in place), 2 rows/block, 16B/lane
__global__ __launch_bounds__(256) void k_softmax(ushort* __restrict__ E)
{
    int t    = threadIdx.x;
    int rowi = t >> 7;                       // 0,1
    int tl   = t & 127;
    ushort* row = E + (size_t)(blockIdx.x * 2 + rowi) * HWSZ;
    uint4 u = *(const uint4*)&row[tl * 8];
    float v[8];
    v[0] = h2f(u.x & 0xffff); v[1] = h2f(u.x >> 16);
    v[2] = h2f(u.y & 0xffff); v[3] = h2f(u.y >> 16);
    v[4] = h2f(u.z & 0xffff); v[5] = h2f(u.z >> 16);
    v[6] = h2f(u.w & 0xffff); v[7] = h2f(u.w >> 16);
    float mx = v[0];
    #pragma unroll
    for (int i = 1; i < 8; ++i) mx = fmaxf(mx, v[i]);
    #pragma unroll
    for (int off = 1; off < 64; off <<= 1)
        mx = fmaxf(mx, __shfl_xor(mx, off));
    __shared__ float redm[2][2];
    __shared__ float reds[2][2];
    int lane = t & 63, wv = (t >> 6) & 1;
    if (lane == 0) redm[rowi][wv] = mx;
    __syncthreads();
    mx = fmaxf(redm[rowi][0], redm[rowi][1]);
    float s = 0.f;
    #pragma unroll
    for (int i = 0; i < 8; ++i) { v[i] = __expf(v[i] - mx); s += v[i]; }
    #pragma unroll
    for (int off = 1; off < 64; off <<= 1)
        s += __shfl_xor(s, off);
    if (lane == 0) reds[rowi][wv] = s;
    __syncthreads();
    s = reds[rowi][0] + reds[rowi][1];
    float inv = 1.0f / s;
    uint4 o;
    o.x = (unsigned)f2h(v[0] * inv) | ((unsigned)f2h(v[1] * inv) << 16);
    o.y = (unsigned)f2h(v[2] * inv) | ((unsigned)f2h(v[3] * inv) << 16);
    o.z = (unsigned)f2h(v[4] * inv) | ((unsigned)f2h(v[5] * inv) << 16);
    o.w = (unsigned)f2h(v[6] * inv) | ((unsigned)f2h(v[7] * inv) << 16);
    *(uint4*)&row[tl * 8] = o;
}

extern "C" void kernel_launch(void* const* d_in, const int* in_sizes, int n_in,
                              void* d_out, int out_size, void* d_ws, size_t ws_size,
                              hipStream_t stream)
{
    const float* x    = (const float*)d_in[0];
    const float* Wk   = (const float*)d_in[1];
    const float* bk   = (const float*)d_in[2];
    const float* Wp   = (const float*)d_in[3];
    const float* bp   = (const float*)d_in[4];
    const float* Wv   = (const float*)d_in[5];
    const float* bv   = (const float*)d_in[6];
    const float* prm  = (const float*)d_in[7];
    float* out = (float*)d_out;
    char* ws = (char*)d_ws;

    // workspace layout (bytes)
    const size_t SZ16 = (size_t)BATCH * HWSZ * CCH * 2;   // 33.55 MB
    ushort* xt    = (ushort*)(ws + 0);
    ushort* KPt   = (ushort*)(ws + SZ16);
    ushort* fv    = (ushort*)(ws + 2 * SZ16);
    ushort* E     = (ushort*)(ws + 3 * SZ16);             // fp16, 67.1 MB
    char* wbase   = ws + 3 * SZ16 + (size_t)BATCH * HWSZ * HWSZ * 2;
    ushort* Wkp_h = (ushort*)(wbase);
    ushort* Wv_h  = (ushort*)(wbase + 524288);
    float*  bias_kp = (float*)(wbase + 2 * 524288);

    // 1) fused weight prep + x transpose
    k_pre<<<dim3(16, 8, 33), 256, 0, stream>>>(
        x, xt, Wk, bk, Wp, bp, Wv, Wkp_h, Wv_h, bias_kp);

    // 2) key/prod projection (128-tile, 2 blk/CU): KPt = xt * Wkp^T (+col bias)
    k_gemm128<0><<<dim3(256, 2, 1), 512, 0, stream>>>(
        xt, Wkp_h, CCH, CCH, 0, 0,
        KPt, 0, CCH, bias_kp, CCH / 32);

    // 3) value projection (128-tile): fv[b][c][m] (+row bias)
    k_gemm128<1><<<dim3(4, 4, 32), 512, 0, stream>>>(
        Wv_h, xt, CCH, CCH, 0, (long)HWSZ * CCH,
        fv, (long)CCH * HWSZ, HWSZ, bv, CCH / 32);

    // 4) energy (256-tile): E[b][n][m] = Kt . Pt^T  (fp16 out)
    k_gemm256<2><<<dim3(4, 4, 32), 512, 0, stream>>>(
        KPt, KPt + RCH, CCH, CCH,
        (long)HWSZ * CCH, (long)HWSZ * CCH,
        nullptr, E, (long)HWSZ * HWSZ, HWSZ,
        nullptr, nullptr, RCH / 64);

    // 5) softmax rows -> sim fp16 (in place), 2 rows/block
    k_softmax<<<BATCH * HWSZ / 2, 256, 0, stream>>>(E);

    // 6) PV + residual (256-tile): out = x + (sim x fv^T)^T * param
    k_gemm256<3><<<dim3(4, 2, 32), 512, 0, stream>>>(
        E, fv, HWSZ, HWSZ,
        (long)HWSZ * HWSZ, (long)CCH * HWSZ,
        out, nullptr, (long)CCH * HWSZ, HWSZ,
        x, prm, HWSZ / 64);
}